// Round 3
// baseline (177.849 us; speedup 1.0000x reference)
//
#include <hip/hip_runtime.h>
#include <hip/hip_bf16.h>

#define BB 2
#define NN 256
#define IN_DIM 256
#define EDGE_DIM 16
#define HH 8
#define DD 64
#define INNER 512
#define BH (BB*HH)

// out = nodes @ W + bias, written in heads layout.
// mode 0: out[((b*H+h)*N + n)*D + d]   (q, v: row-major per head)
// mode 1: out[((b*H+h)*D + d)*N + n]   (k: transposed per head)
__global__ void proj_kernel(const float* __restrict__ nodes,
                            const float* __restrict__ W,
                            const float* __restrict__ bias,
                            float* __restrict__ out, int mode) {
    __shared__ float nsh[8][IN_DIM];
    const int tid = threadIdx.x;
    const int half = blockIdx.x;   // 0..1 (column half)
    const int rt = blockIdx.y;     // 0..63 (row tile of 8)
    const int r0 = rt * 8;
    for (int idx = tid; idx < 8 * IN_DIM; idx += 256) {
        int rr = idx >> 8, k = idx & (IN_DIM - 1);
        nsh[rr][k] = nodes[(r0 + rr) * IN_DIM + k];
    }
    __syncthreads();
    const int col = half * 256 + tid;
    float acc[8];
#pragma unroll
    for (int rr = 0; rr < 8; ++rr) acc[rr] = 0.f;
    for (int k = 0; k < IN_DIM; ++k) {
        float wv = W[k * INNER + col];
#pragma unroll
        for (int rr = 0; rr < 8; ++rr) acc[rr] += nsh[rr][k] * wv;
    }
    const float bv = bias[col];
    const int h = col >> 6, d = col & 63;
#pragma unroll
    for (int rr = 0; rr < 8; ++rr) {
        int r = r0 + rr;
        int b = r >> 8, n = r & 255;
        float val = acc[rr] + bv;
        if (mode == 0)
            out[((b * HH + h) * NN + n) * DD + d] = val;
        else
            out[((b * HH + h) * DD + d) * NN + n] = val;
    }
}

// means[i] = mean_j sim[bh=0, i, j]   (the reference's [0]-sliced mean)
__global__ void means_kernel(const float* __restrict__ q,   // (BH,N,D)
                             const float* __restrict__ kT,  // (BH,D,N)
                             const float* __restrict__ edges,
                             const float* __restrict__ We,
                             const float* __restrict__ be,
                             float* __restrict__ means) {
    const int i = blockIdx.x;
    const int tid = threadIdx.x;
    __shared__ float qsh[DD];
    __shared__ float tsh[EDGE_DIM + 1];
    __shared__ float wred[4];
    if (tid < DD) qsh[tid] = q[i * DD + tid];    // bh = 0
    __syncthreads();
    if (tid < EDGE_DIM) {
        float s = 0.f;
        for (int d = 0; d < DD; ++d) s += qsh[d] * We[tid * INNER + d];  // h=0
        tsh[tid] = s;
    } else if (tid == EDGE_DIM) {
        float s = 0.f;
        for (int d = 0; d < DD; ++d) s += qsh[d] * be[d];
        tsh[EDGE_DIM] = s;
    }
    __syncthreads();
    const int j = tid;
    float sim = 0.f;
    for (int d = 0; d < DD; ++d) sim += qsh[d] * kT[d * NN + j];  // bh = 0
    float ed = 0.f;
    const float* erow = &edges[(i * NN + j) * EDGE_DIM];          // b = 0
#pragma unroll
    for (int c = 0; c < EDGE_DIM; ++c) ed += erow[c] * tsh[c];
    sim = (sim + ed + tsh[EDGE_DIM]) * 0.125f;
    float s = sim;
    for (int o = 32; o > 0; o >>= 1) s += __shfl_down(s, o, 64);
    if ((tid & 63) == 0) wred[tid >> 6] = s;
    __syncthreads();
    if (tid == 0) means[i] = (wred[0] + wred[1] + wred[2] + wred[3]) * (1.f / NN);
}

// One block per (bh, i): scores -> custom softmax -> attn@v + edge correction.
__global__ void attn_kernel(const float* __restrict__ q,
                            const float* __restrict__ kT,
                            const float* __restrict__ v,
                            const float* __restrict__ edges,
                            const float* __restrict__ adj,
                            const float* __restrict__ We,
                            const float* __restrict__ be,
                            const float* __restrict__ means,
                            float* __restrict__ out) {
    const int blk = blockIdx.x;
    const int bh = blk >> 8;
    const int i = blk & 255;
    const int b = bh >> 3, h = bh & 7;
    const int tid = threadIdx.x;
    __shared__ float qsh[DD];
    __shared__ float tsh[EDGE_DIM + 1];
    __shared__ float attn_sh[NN];
    __shared__ float red[4][DD];
    __shared__ float wred2[EDGE_DIM][EDGE_DIM + 1];
    __shared__ float wsh[EDGE_DIM];
    __shared__ float dred[4];

    if (tid < DD) qsh[tid] = q[(bh * NN + i) * DD + tid];
    __syncthreads();
    if (tid < EDGE_DIM) {
        float s = 0.f;
        for (int d = 0; d < DD; ++d) s += qsh[d] * We[tid * INNER + h * DD + d];
        tsh[tid] = s;
    } else if (tid == EDGE_DIM) {
        float s = 0.f;
        for (int d = 0; d < DD; ++d) s += qsh[d] * be[h * DD + d];
        tsh[EDGE_DIM] = s;
    }
    __syncthreads();

    // --- scores ---
    const int j = tid;
    float sim = 0.f;
    const float* kbase = &kT[bh * DD * NN];
    for (int d = 0; d < DD; ++d) sim += qsh[d] * kbase[d * NN + j];
    float ed = 0.f;
    const float* erow = &edges[((b * NN + i) * NN + j) * EDGE_DIM];
#pragma unroll
    for (int c = 0; c < EDGE_DIM; ++c) ed += erow[c] * tsh[c];
    sim = (sim + ed + tsh[EDGE_DIM]) * 0.125f;

    // --- custom softmax (mean from bh=0, adjacency mask, denom==0 -> 1) ---
    float x = expf(sim - means[i]) * adj[(b * NN + i) * NN + j];
    float s = x;
    for (int o = 32; o > 0; o >>= 1) s += __shfl_down(s, o, 64);
    if ((tid & 63) == 0) dred[tid >> 6] = s;
    __syncthreads();
    float denom = dred[0] + dred[1] + dred[2] + dred[3];
    const float scoef = (denom == 0.f) ? 0.f : 1.f;
    if (denom == 0.f) denom = 1.f;
    attn_sh[j] = x / denom;
    __syncthreads();

    // --- attn @ v (4 partials of 64 j each) ---
    const int d = tid & 63, part = tid >> 6;
    {
        float acc = 0.f;
        const float* vb = &v[(bh * NN + part * 64) * DD + d];
        for (int jj = 0; jj < 64; ++jj)
            acc += attn_sh[part * 64 + jj] * vb[jj * DD];
        red[part][d] = acc;
    }
    // --- w[c] = sum_j attn_ij * edges[b,i,j,c] (16 partials of 16 j each) ---
    {
        const int c = tid & 15, p = tid >> 4;
        float acc = 0.f;
        const float* eb = &edges[((b * NN + i) * NN + p * 16) * EDGE_DIM + c];
        for (int jj = 0; jj < 16; ++jj)
            acc += attn_sh[p * 16 + jj] * eb[jj * EDGE_DIM];
        wred2[p][c] = acc;
    }
    __syncthreads();
    if (tid < EDGE_DIM) {
        float t = 0.f;
        for (int p = 0; p < EDGE_DIM; ++p) t += wred2[p][tid];
        wsh[tid] = t;
    }
    __syncthreads();

    // --- epilogue: out = attn@v + w@We_h + (sum attn)*be_h ---
    if (tid < DD) {
        float o = red[0][tid] + red[1][tid] + red[2][tid] + red[3][tid];
        float extra = scoef * be[h * DD + tid];
#pragma unroll
        for (int c = 0; c < EDGE_DIM; ++c)
            extra += wsh[c] * We[c * INNER + h * DD + tid];
        out[(b * NN + i) * INNER + h * DD + tid] = o + extra;
    }
}

extern "C" void kernel_launch(void* const* d_in, const int* in_sizes, int n_in,
                              void* d_out, int out_size, void* d_ws, size_t ws_size,
                              hipStream_t stream) {
    const float* nodes = (const float*)d_in[0];
    const float* edges = (const float*)d_in[1];
    const float* adj   = (const float*)d_in[2];
    const float* Wq = (const float*)d_in[3];
    const float* bq = (const float*)d_in[4];
    const float* Wk = (const float*)d_in[5];
    const float* bk = (const float*)d_in[6];
    const float* Wv = (const float*)d_in[7];
    const float* bv = (const float*)d_in[8];
    const float* We = (const float*)d_in[9];
    const float* be = (const float*)d_in[10];
    float* out = (float*)d_out;

    float* qf = (float*)d_ws;            // BH*N*D
    float* kT = qf + BH * NN * DD;       // BH*D*N
    float* vf = kT + BH * NN * DD;       // BH*N*D
    float* means = vf + BH * NN * DD;    // N

    dim3 pgrid(2, 64);
    hipLaunchKernelGGL(proj_kernel, pgrid, dim3(256), 0, stream, nodes, Wq, bq, qf, 0);
    hipLaunchKernelGGL(proj_kernel, pgrid, dim3(256), 0, stream, nodes, Wk, bk, kT, 1);
    hipLaunchKernelGGL(proj_kernel, pgrid, dim3(256), 0, stream, nodes, Wv, bv, vf, 0);
    hipLaunchKernelGGL(means_kernel, dim3(NN), dim3(256), 0, stream, qf, kT, edges, We, be, means);
    hipLaunchKernelGGL(attn_kernel, dim3(BH * NN), dim3(256), 0, stream,
                       qf, kT, vf, edges, adj, We, be, means, out);
}

// Round 4
// 162.190 us; speedup vs baseline: 1.0965x; 1.0965x over previous
//
#include <hip/hip_runtime.h>
#include <hip/hip_bf16.h>

#define BB 2
#define NN 256
#define IN_DIM 256
#define EDGE_DIM 16
#define HH 8
#define DD 64
#define INNER 512
#define BH (BB*HH)
#define II 8   // i-rows per attn block

// Fused q/k/v projection: out = nodes @ W + bias in heads layout.
// z==0: q row-major  z==1: k transposed  z==2: v row-major
__global__ void proj_kernel(const float* __restrict__ nodes,
                            const float* __restrict__ Wq, const float* __restrict__ bq,
                            const float* __restrict__ Wk, const float* __restrict__ bk,
                            const float* __restrict__ Wv, const float* __restrict__ bv,
                            float* __restrict__ qf, float* __restrict__ kT,
                            float* __restrict__ vf) {
    const int z = blockIdx.z;
    const float* W; const float* bias; float* out; int mode;
    if (z == 0)      { W = Wq; bias = bq; out = qf; mode = 0; }
    else if (z == 1) { W = Wk; bias = bk; out = kT; mode = 1; }
    else             { W = Wv; bias = bv; out = vf; mode = 0; }

    __shared__ float nsh[8][IN_DIM];
    const int tid = threadIdx.x;
    const int half = blockIdx.x;   // 0..1 (column half)
    const int rt = blockIdx.y;     // 0..63 (row tile of 8)
    const int r0 = rt * 8;
    for (int idx = tid; idx < 8 * IN_DIM; idx += 256) {
        int rr = idx >> 8, k = idx & (IN_DIM - 1);
        nsh[rr][k] = nodes[(r0 + rr) * IN_DIM + k];
    }
    __syncthreads();
    const int col = half * 256 + tid;
    float acc[8];
#pragma unroll
    for (int rr = 0; rr < 8; ++rr) acc[rr] = 0.f;
    for (int k = 0; k < IN_DIM; ++k) {
        float wv = W[k * INNER + col];
#pragma unroll
        for (int rr = 0; rr < 8; ++rr) acc[rr] += nsh[rr][k] * wv;
    }
    const float bv2 = bias[col];
    const int h = col >> 6, d = col & 63;
#pragma unroll
    for (int rr = 0; rr < 8; ++rr) {
        int r = r0 + rr;
        int b = r >> 8, n = r & 255;
        float val = acc[rr] + bv2;
        if (mode == 0)
            out[((b * HH + h) * NN + n) * DD + d] = val;
        else
            out[((b * HH + h) * DD + d) * NN + n] = val;
    }
}

// means[i] = mean_j sim[bh=0, i, j]   (the reference's [0]-sliced mean)
__global__ void means_kernel(const float* __restrict__ q,   // (BH,N,D)
                             const float* __restrict__ kT,  // (BH,D,N)
                             const float* __restrict__ edges,
                             const float* __restrict__ We,
                             const float* __restrict__ be,
                             float* __restrict__ means) {
    const int i = blockIdx.x;
    const int tid = threadIdx.x;
    __shared__ float qsh[DD];
    __shared__ float tsh[EDGE_DIM + 1];
    __shared__ float wred[4];
    if (tid < DD) qsh[tid] = q[i * DD + tid];    // bh = 0
    __syncthreads();
    if (tid < EDGE_DIM) {
        float s = 0.f;
        for (int d = 0; d < DD; ++d) s += qsh[d] * We[tid * INNER + d];  // h=0
        tsh[tid] = s;
    } else if (tid == EDGE_DIM) {
        float s = 0.f;
        for (int d = 0; d < DD; ++d) s += qsh[d] * be[d];
        tsh[EDGE_DIM] = s;
    }
    __syncthreads();
    const int j = tid;
    float sim = 0.f;
    for (int d = 0; d < DD; ++d) sim += qsh[d] * kT[d * NN + j];  // bh = 0
    float ed = 0.f;
    const float* erow = &edges[(i * NN + j) * EDGE_DIM];          // b = 0
#pragma unroll
    for (int c = 0; c < EDGE_DIM; ++c) ed += erow[c] * tsh[c];
    sim = (sim + ed + tsh[EDGE_DIM]) * 0.125f;
    float s = sim;
    for (int o = 32; o > 0; o >>= 1) s += __shfl_down(s, o, 64);
    if ((tid & 63) == 0) wred[tid >> 6] = s;
    __syncthreads();
    if (tid == 0) means[i] = (wred[0] + wred[1] + wred[2] + wred[3]) * (1.f / NN);
}

// One block per (bh, i-tile of II rows): scores -> softmax -> attn@v + edge terms.
// kT and v are read once per block and reused II times.
__global__ void attn_kernel(const float* __restrict__ q,
                            const float* __restrict__ kT,
                            const float* __restrict__ v,
                            const float* __restrict__ edges,
                            const float* __restrict__ adj,
                            const float* __restrict__ We,
                            const float* __restrict__ be,
                            const float* __restrict__ means,
                            float* __restrict__ out) {
    const int blk = blockIdx.x;           // BH * (NN/II) = 512
    const int bh = blk >> 5;              // 32 i-tiles per bh
    const int it = blk & 31;
    const int i0 = it * II;
    const int b = bh >> 3, h = bh & 7;
    const int tid = threadIdx.x;

    __shared__ float qsh[II][DD];
    __shared__ float tsh[II][EDGE_DIM + 1];
    __shared__ float attn_sh[II][NN];
    __shared__ float red[4][II][DD];
    __shared__ float wred2[16][II][EDGE_DIM];
    __shared__ float wsh[II][EDGE_DIM];
    __shared__ float dred[II][4];
    __shared__ float msh[II];
    __shared__ float dsh[II];
    __shared__ float scoef_sh[II];

    for (int idx = tid; idx < II * DD; idx += 256) {
        int ii = idx >> 6, d = idx & 63;
        qsh[ii][d] = q[(bh * NN + i0 + ii) * DD + d];
    }
    if (tid < II) msh[tid] = means[i0 + tid];
    __syncthreads();

    if (tid < II * (EDGE_DIM + 1)) {
        int ii = tid / (EDGE_DIM + 1), c = tid % (EDGE_DIM + 1);
        float s = 0.f;
        if (c < EDGE_DIM) {
            for (int d = 0; d < DD; ++d) s += qsh[ii][d] * We[c * INNER + h * DD + d];
        } else {
            for (int d = 0; d < DD; ++d) s += qsh[ii][d] * be[h * DD + d];
        }
        tsh[ii][c] = s;
    }
    __syncthreads();

    // --- scores: kT read once, reused II times ---
    const int j = tid;
    float sim[II];
#pragma unroll
    for (int ii = 0; ii < II; ++ii) sim[ii] = 0.f;
    const float* kbase = &kT[bh * DD * NN];
    for (int d = 0; d < DD; ++d) {
        float kv = kbase[d * NN + j];
#pragma unroll
        for (int ii = 0; ii < II; ++ii) sim[ii] += qsh[ii][d] * kv;
    }
    float x[II];
#pragma unroll
    for (int ii = 0; ii < II; ++ii) {
        const float* erow = &edges[((b * NN + i0 + ii) * NN + j) * EDGE_DIM];
        float ed = tsh[ii][EDGE_DIM];
#pragma unroll
        for (int c = 0; c < EDGE_DIM; ++c) ed += erow[c] * tsh[ii][c];
        sim[ii] = (sim[ii] + ed) * 0.125f;
        x[ii] = __expf(sim[ii] - msh[ii]) * adj[(b * NN + i0 + ii) * NN + j];
    }

    // --- block-wide denominators (custom softmax: denom==0 -> 1) ---
#pragma unroll
    for (int ii = 0; ii < II; ++ii) {
        float s = x[ii];
        for (int o = 32; o > 0; o >>= 1) s += __shfl_down(s, o, 64);
        if ((tid & 63) == 0) dred[ii][tid >> 6] = s;
    }
    __syncthreads();
    if (tid < II) {
        float denom = dred[tid][0] + dred[tid][1] + dred[tid][2] + dred[tid][3];
        scoef_sh[tid] = (denom == 0.f) ? 0.f : 1.f;
        dsh[tid] = (denom == 0.f) ? 1.f : denom;
    }
    __syncthreads();
#pragma unroll
    for (int ii = 0; ii < II; ++ii) attn_sh[ii][j] = x[ii] / dsh[ii];
    __syncthreads();

    // --- attn @ v: v read once, reused II times ---
    {
        const int d = tid & 63, part = tid >> 6;
        float acc[II];
#pragma unroll
        for (int ii = 0; ii < II; ++ii) acc[ii] = 0.f;
        const float* vb = &v[(bh * NN + part * 64) * DD + d];
        for (int jj = 0; jj < 64; ++jj) {
            float av = vb[jj * DD];
#pragma unroll
            for (int ii = 0; ii < II; ++ii) acc[ii] += attn_sh[ii][part * 64 + jj] * av;
        }
#pragma unroll
        for (int ii = 0; ii < II; ++ii) red[part][ii][d] = acc[ii];
    }
    // --- w[ii][c] = sum_j attn[ii][j] * edges[b, i0+ii, j, c] ---
    {
        const int c = tid & 15, p = tid >> 4;
        float accw[II];
#pragma unroll
        for (int ii = 0; ii < II; ++ii) accw[ii] = 0.f;
        for (int jj = 0; jj < 16; ++jj) {
            int jrow = p * 16 + jj;
#pragma unroll
            for (int ii = 0; ii < II; ++ii)
                accw[ii] += attn_sh[ii][jrow] *
                            edges[((b * NN + i0 + ii) * NN + jrow) * EDGE_DIM + c];
        }
#pragma unroll
        for (int ii = 0; ii < II; ++ii) wred2[p][ii][c] = accw[ii];
    }
    __syncthreads();
    if (tid < II * EDGE_DIM) {
        int ii = tid >> 4, c = tid & 15;
        float t = 0.f;
#pragma unroll
        for (int p = 0; p < 16; ++p) t += wred2[p][ii][c];
        wsh[ii][c] = t;
    }
    __syncthreads();

    // --- epilogue ---
    for (int idx = tid; idx < II * DD; idx += 256) {
        int ii = idx >> 6, d = idx & 63;
        float o = red[0][ii][d] + red[1][ii][d] + red[2][ii][d] + red[3][ii][d];
        float extra = scoef_sh[ii] * be[h * DD + d];
#pragma unroll
        for (int c = 0; c < EDGE_DIM; ++c)
            extra += wsh[ii][c] * We[c * INNER + h * DD + d];
        out[(b * NN + i0 + ii) * INNER + h * DD + d] = o + extra;
    }
}

extern "C" void kernel_launch(void* const* d_in, const int* in_sizes, int n_in,
                              void* d_out, int out_size, void* d_ws, size_t ws_size,
                              hipStream_t stream) {
    const float* nodes = (const float*)d_in[0];
    const float* edges = (const float*)d_in[1];
    const float* adj   = (const float*)d_in[2];
    const float* Wq = (const float*)d_in[3];
    const float* bq = (const float*)d_in[4];
    const float* Wk = (const float*)d_in[5];
    const float* bk = (const float*)d_in[6];
    const float* Wv = (const float*)d_in[7];
    const float* bv = (const float*)d_in[8];
    const float* We = (const float*)d_in[9];
    const float* be = (const float*)d_in[10];
    float* out = (float*)d_out;

    float* qf = (float*)d_ws;            // BH*N*D
    float* kT = qf + BH * NN * DD;       // BH*D*N
    float* vf = kT + BH * NN * DD;       // BH*N*D
    float* means = vf + BH * NN * DD;    // N

    hipLaunchKernelGGL(proj_kernel, dim3(2, 64, 3), dim3(256), 0, stream,
                       nodes, Wq, bq, Wk, bk, Wv, bv, qf, kT, vf);
    hipLaunchKernelGGL(means_kernel, dim3(NN), dim3(256), 0, stream,
                       qf, kT, edges, We, be, means);
    hipLaunchKernelGGL(attn_kernel, dim3(BH * (NN / II)), dim3(256), 0, stream,
                       qf, kT, vf, edges, adj, We, be, means, out);
}